// Round 3
// baseline (349.523 us; speedup 1.0000x reference)
//
#include <hip/hip_runtime.h>
#include <math.h>

#define T 2048
#define HD 1024
#define ID 2048
#define NE 8
#define CSTRIDE 32  // counters padded to 128B lines

typedef short bf16x8 __attribute__((ext_vector_type(8)));
typedef float f32x4 __attribute__((ext_vector_type(4)));
typedef unsigned short u16x4 __attribute__((ext_vector_type(4)));
typedef unsigned short u16x8 __attribute__((ext_vector_type(8)));

__device__ __forceinline__ unsigned short f2bf(float f) {
  union { float f; unsigned u; } v; v.f = f;
  unsigned r = v.u + 0x7FFFu + ((v.u >> 16) & 1u);
  return (unsigned short)(r >> 16);
}

__device__ __forceinline__ u16x8 cvt8(float4 a, float4 b) {
  u16x8 o;
  o[0] = f2bf(a.x); o[1] = f2bf(a.y); o[2] = f2bf(a.z); o[3] = f2bf(a.w);
  o[4] = f2bf(b.x); o[5] = f2bf(b.y); o[6] = f2bf(b.z); o[7] = f2bf(b.w);
  return o;
}

// cast 4096 fp32 -> bf16 per block; lane-contiguous float4 loads
__device__ __forceinline__ void cast_chunk16(const float* __restrict__ s,
                                             unsigned short* __restrict__ d,
                                             size_t base) {
  size_t o = base + (size_t)threadIdx.x * 4;
#pragma unroll
  for (int k = 0; k < 4; k++) {
    float4 f = *(const float4*)(s + o + k * 1024);
    u16x4 h;
    h[0] = f2bf(f.x); h[1] = f2bf(f.y); h[2] = f2bf(f.z); h[3] = f2bf(f.w);
    *(u16x4*)(d + o + k * 1024) = h;
  }
}

// ---------- prep: router (blocks 0..255, 8 tokens each) + cast_x (256..767) ----------
__global__ __launch_bounds__(256) void prep_kernel(
    const float* __restrict__ x, const float* __restrict__ rw,
    unsigned short* __restrict__ xb, float* __restrict__ logits_out,
    int* __restrict__ pair_rowid, float* __restrict__ pair_gate,
    int* __restrict__ counts) {
  int bx = blockIdx.x;
  if (bx >= 256) {
    cast_chunk16(x, xb, (size_t)(bx - 256) * 4096);
    return;
  }
  __shared__ int s_e[16];
  __shared__ int s_rid[16];
  __shared__ float s_gt[16];
  int tid = threadIdx.x;
  int wid = tid >> 6, lane = tid & 63;
  for (int tk = 0; tk < 2; ++tk) {
    int t = bx * 8 + wid * 2 + tk;
    float acc[NE];
#pragma unroll
    for (int e = 0; e < NE; e++) acc[e] = 0.f;
    const float* xrow = x + (size_t)t * HD;
#pragma unroll 2
    for (int j = 0; j < HD; j += 64) {
      float xv = xrow[j + lane];
#pragma unroll
      for (int e = 0; e < NE; e++) acc[e] += xv * rw[e * HD + j + lane];
    }
#pragma unroll
    for (int e = 0; e < NE; e++)
      for (int off = 32; off > 0; off >>= 1) acc[e] += __shfl_xor(acc[e], off, 64);
    if (lane == 0) {
#pragma unroll
      for (int e = 0; e < NE; e++) logits_out[t * NE + e] = acc[e];
      int e0 = 0;
#pragma unroll
      for (int e = 1; e < NE; e++) if (acc[e] > acc[e0]) e0 = e;
      int e1 = (e0 == 0) ? 1 : 0;
#pragma unroll
      for (int e = 0; e < NE; e++)
        if (e != e0 && e != e1 && acc[e] > acc[e1]) e1 = e;
      float b = __expf(acc[e1] - acc[e0]);
      float g0 = 1.f / (1.f + b);
      float g1 = 1.f - g0;
      int slot = (wid * 2 + tk) * 2;
      s_e[slot] = e0; s_rid[slot] = t * 2;     s_gt[slot] = g0;
      s_e[slot + 1] = e1; s_rid[slot + 1] = t * 2 + 1; s_gt[slot + 1] = g1;
    }
  }
  __syncthreads();
  if (tid < NE) {
    int cnt = 0;
#pragma unroll
    for (int k = 0; k < 16; k++) if (s_e[k] == tid) cnt++;
    if (cnt) {
      int base = atomicAdd(&counts[tid * CSTRIDE], cnt);
      int p = 0;
      for (int k = 0; k < 16; k++)
        if (s_e[k] == tid) {
          pair_rowid[tid * T + base + p] = s_rid[k];
          pair_gate[tid * T + base + p] = s_gt[k];
          p++;
        }
    }
  }
}

// ---------- GEMM1: 128(M)x64(N), BK=64, single-buffer LDS (32 KB),
//            reg-staged A+B with issue-early/commit-late (T14) ----------
__global__ __launch_bounds__(256) void gemm1_kernel(
    const unsigned short* __restrict__ xb, const float* __restrict__ w1,
    const float* __restrict__ v, unsigned short* __restrict__ hb,
    const int* __restrict__ pair_rowid, const int* __restrict__ counts) {
  int e = blockIdx.z;
  int cnt = counts[e * CSTRIDE];
  int row0 = blockIdx.y * 128;
  if (row0 >= cnt) return;
  __shared__ unsigned short As[128 * 64];   // 16 KB
  __shared__ unsigned short B1s[64 * 64];   // 8 KB
  __shared__ unsigned short B2s[64 * 64];   // 8 KB
  int tid = threadIdx.x;
  int lane = tid & 63, wid = tid >> 6;
  int wr = wid >> 1, wc = wid & 1;
  int col0 = blockIdx.x * 64;
  int gr = lane >> 3, gc = lane & 7;
  const unsigned short *aA[4];
  const float *aB1[2], *aB2[2];
#pragma unroll
  for (int c = 0; c < 4; c++) {
    int row = (c * 4 + wid) * 8 + gr;
    int idx = row0 + row; if (idx > cnt - 1) idx = cnt - 1;
    int tok = pair_rowid[e * T + idx] >> 1;
    aA[c] = xb + (size_t)tok * HD + ((gc ^ (row & 7)) * 8);
  }
#pragma unroll
  for (int c = 0; c < 2; c++) {
    int row = (c * 4 + wid) * 8 + gr;
    int kswz = ((gc ^ (row & 7)) * 8);
    aB1[c] = w1 + ((size_t)(e * ID + col0 + row)) * HD + kswz;
    aB2[c] = v  + ((size_t)(e * ID + col0 + row)) * HD + kswz;
  }
  f32x4 acc1[4][2] = {};
  f32x4 acc3[4][2] = {};
  int mrow = lane & 15, kq = lane >> 4;
  int swzm = mrow & 7;
  u16x8 rA[4];
  float4 rb1[2][2], rb2[2][2];

  auto loads = [&](int kt) {   // global -> regs only; no LDS touch
#pragma unroll
    for (int c = 0; c < 4; c++) rA[c] = *(const u16x8*)(aA[c] + kt);
#pragma unroll
    for (int c = 0; c < 2; c++) {
      rb1[c][0] = *(const float4*)(aB1[c] + kt);
      rb1[c][1] = *(const float4*)(aB1[c] + kt + 4);
      rb2[c][0] = *(const float4*)(aB2[c] + kt);
      rb2[c][1] = *(const float4*)(aB2[c] + kt + 4);
    }
  };
  auto commit = [&]() {        // regs -> LDS (cvt fused for B)
#pragma unroll
    for (int c = 0; c < 4; c++)
      *(u16x8*)&As[(c * 4 + wid) * 512 + lane * 8] = rA[c];
#pragma unroll
    for (int c = 0; c < 2; c++) {
      *(u16x8*)&B1s[(c * 4 + wid) * 512 + lane * 8] = cvt8(rb1[c][0], rb1[c][1]);
      *(u16x8*)&B2s[(c * 4 + wid) * 512 + lane * 8] = cvt8(rb2[c][0], rb2[c][1]);
    }
  };
  auto compute = [&]() {
#pragma unroll
    for (int kk = 0; kk < 2; kk++) {
      int g = kk * 4 + kq;
      int ko = ((g ^ swzm) * 8);
      bf16x8 a[4], b1[2], b2[2];
#pragma unroll
      for (int mi = 0; mi < 4; mi++)
        a[mi] = *(const bf16x8*)&As[(wr * 64 + mi * 16 + mrow) * 64 + ko];
#pragma unroll
      for (int ni = 0; ni < 2; ni++) {
        b1[ni] = *(const bf16x8*)&B1s[(wc * 32 + ni * 16 + mrow) * 64 + ko];
        b2[ni] = *(const bf16x8*)&B2s[(wc * 32 + ni * 16 + mrow) * 64 + ko];
      }
#pragma unroll
      for (int mi = 0; mi < 4; mi++)
#pragma unroll
        for (int ni = 0; ni < 2; ni++) {
          acc1[mi][ni] = __builtin_amdgcn_mfma_f32_16x16x32_bf16(a[mi], b1[ni], acc1[mi][ni], 0, 0, 0);
          acc3[mi][ni] = __builtin_amdgcn_mfma_f32_16x16x32_bf16(a[mi], b2[ni], acc3[mi][ni], 0, 0, 0);
        }
    }
  };

  loads(0);
  commit();
  __syncthreads();
#pragma unroll 1
  for (int t = 0; t < 16; ++t) {
    if (t < 15) loads((t + 1) * 64);   // next-tile loads hide under compute(t)
    compute();
    __syncthreads();                   // readers of tile t done
    if (t < 15) { commit(); __syncthreads(); }
  }

  int dcol = lane & 15, drow4 = (lane >> 4) * 4;
#pragma unroll
  for (int mi = 0; mi < 4; mi++)
#pragma unroll
    for (int ni = 0; ni < 2; ni++)
#pragma unroll
      for (int r = 0; r < 4; r++) {
        int lr = wr * 64 + mi * 16 + drow4 + r;
        if (row0 + lr < cnt) {
          float g1v = acc1[mi][ni][r];
          float g3v = acc3[mi][ni][r];
          float hval = 0.5f * g1v * (1.f + erff(g1v * 0.70710678118654752f)) * g3v;
          int rowid = pair_rowid[e * T + row0 + lr];
          hb[(size_t)rowid * ID + col0 + wc * 32 + ni * 16 + dcol] = f2bf(hval);
        }
      }
}

// ---------- GEMM2: 128(M)x64(N), BK=64, single-buffer (24 KB), same pipeline ----------
__global__ __launch_bounds__(256) void gemm2_kernel(
    const unsigned short* __restrict__ hb, const float* __restrict__ w2,
    float* __restrict__ yb, const int* __restrict__ pair_rowid,
    const float* __restrict__ pair_gate, const int* __restrict__ counts) {
  int e = blockIdx.z;
  int cnt = counts[e * CSTRIDE];
  int row0 = blockIdx.y * 128;
  if (row0 >= cnt) return;
  __shared__ unsigned short As[128 * 64];   // 16 KB
  __shared__ unsigned short Bs[64 * 64];    // 8 KB
  int tid = threadIdx.x;
  int lane = tid & 63, wid = tid >> 6;
  int wr = wid >> 1, wc = wid & 1;
  int col0 = blockIdx.x * 64;
  int gr = lane >> 3, gc = lane & 7;
  const unsigned short *aA[4];
  const float *aB[2];
#pragma unroll
  for (int c = 0; c < 4; c++) {
    int row = (c * 4 + wid) * 8 + gr;
    int idx = row0 + row; if (idx > cnt - 1) idx = cnt - 1;
    aA[c] = hb + (size_t)pair_rowid[e * T + idx] * ID + ((gc ^ (row & 7)) * 8);
  }
#pragma unroll
  for (int c = 0; c < 2; c++) {
    int row = (c * 4 + wid) * 8 + gr;
    int kswz = ((gc ^ (row & 7)) * 8);
    aB[c] = w2 + ((size_t)(e * HD + col0 + row)) * ID + kswz;
  }
  f32x4 acc[4][2] = {};
  int mrow = lane & 15, kq = lane >> 4;
  int swzm = mrow & 7;
  u16x8 rA[4];
  float4 rb[2][2];

  auto loads = [&](int kt) {
#pragma unroll
    for (int c = 0; c < 4; c++) rA[c] = *(const u16x8*)(aA[c] + kt);
#pragma unroll
    for (int c = 0; c < 2; c++) {
      rb[c][0] = *(const float4*)(aB[c] + kt);
      rb[c][1] = *(const float4*)(aB[c] + kt + 4);
    }
  };
  auto commit = [&]() {
#pragma unroll
    for (int c = 0; c < 4; c++)
      *(u16x8*)&As[(c * 4 + wid) * 512 + lane * 8] = rA[c];
#pragma unroll
    for (int c = 0; c < 2; c++)
      *(u16x8*)&Bs[(c * 4 + wid) * 512 + lane * 8] = cvt8(rb[c][0], rb[c][1]);
  };
  auto compute = [&]() {
#pragma unroll
    for (int kk = 0; kk < 2; kk++) {
      int g = kk * 4 + kq;
      int ko = ((g ^ swzm) * 8);
      bf16x8 a[4], b[2];
#pragma unroll
      for (int mi = 0; mi < 4; mi++)
        a[mi] = *(const bf16x8*)&As[(wr * 64 + mi * 16 + mrow) * 64 + ko];
#pragma unroll
      for (int ni = 0; ni < 2; ni++)
        b[ni] = *(const bf16x8*)&Bs[(wc * 32 + ni * 16 + mrow) * 64 + ko];
#pragma unroll
      for (int mi = 0; mi < 4; mi++)
#pragma unroll
        for (int ni = 0; ni < 2; ni++)
          acc[mi][ni] = __builtin_amdgcn_mfma_f32_16x16x32_bf16(a[mi], b[ni], acc[mi][ni], 0, 0, 0);
    }
  };

  loads(0);
  commit();
  __syncthreads();
#pragma unroll 1
  for (int t = 0; t < 32; ++t) {
    if (t < 31) loads((t + 1) * 64);
    compute();
    __syncthreads();
    if (t < 31) { commit(); __syncthreads(); }
  }

  int dcol = lane & 15, drow4 = (lane >> 4) * 4;
#pragma unroll
  for (int mi = 0; mi < 4; mi++)
#pragma unroll
    for (int ni = 0; ni < 2; ni++)
#pragma unroll
      for (int r = 0; r < 4; r++) {
        int lr = wr * 64 + mi * 16 + drow4 + r;
        if (row0 + lr < cnt) {
          float val = pair_gate[e * T + row0 + lr] * acc[mi][ni][r];
          yb[(size_t)pair_rowid[e * T + row0 + lr] * HD + col0 + wc * 32 + ni * 16 + dcol] = val;
        }
      }
}

// ---------- combine: out[t] = yb[2t] + yb[2t+1] ----------
__global__ __launch_bounds__(256) void combine_kernel(
    const float* __restrict__ yb, float* __restrict__ out) {
  size_t t = blockIdx.x;
  int c = threadIdx.x * 4;
  float4 a = *(const float4*)(yb + (t * 2) * HD + c);
  float4 b = *(const float4*)(yb + (t * 2 + 1) * HD + c);
  float4 o;
  o.x = a.x + b.x; o.y = a.y + b.y; o.z = a.z + b.z; o.w = a.w + b.w;
  *(float4*)(out + t * HD + c) = o;
}

extern "C" void kernel_launch(void* const* d_in, const int* in_sizes, int n_in,
                              void* d_out, int out_size, void* d_ws, size_t ws_size,
                              hipStream_t stream) {
  const float* x  = (const float*)d_in[0];
  const float* rw = (const float*)d_in[1];
  const float* w1 = (const float*)d_in[2];
  const float* v  = (const float*)d_in[3];
  const float* w2 = (const float*)d_in[4];
  float* out = (float*)d_out;
  float* logits_out = out + (size_t)T * HD;

  char* ws = (char*)d_ws;
  unsigned short* xb  = (unsigned short*)(ws);                      // 4 MB
  unsigned short* hb  = (unsigned short*)(ws + (4u << 20));         // 16 MB
  float* yb           = (float*)(ws + (20u << 20));                 // 16 MB
  int*   pair_rowid   = (int*)  (ws + (116u << 20));                // 64 KB
  float* pair_gate    = (float*)(ws + (116u << 20) + 65536);        // 64 KB
  int*   counts       = (int*)  (ws + (116u << 20) + 131072);       // 1 KB

  hipMemsetAsync(counts, 0, NE * CSTRIDE * sizeof(int), stream);

  prep_kernel<<<768, 256, 0, stream>>>(x, rw, xb, logits_out, pair_rowid,
                                       pair_gate, counts);
  gemm1_kernel<<<dim3(ID / 64, T / 128, NE), 256, 0, stream>>>(
      xb, w1, v, hb, pair_rowid, counts);
  gemm2_kernel<<<dim3(HD / 64, T / 128, NE), 256, 0, stream>>>(
      hb, w2, yb, pair_rowid, pair_gate, counts);
  combine_kernel<<<T, 256, 0, stream>>>(yb, out);
}

// Round 4
// 320.516 us; speedup vs baseline: 1.0905x; 1.0905x over previous
//
#include <hip/hip_runtime.h>
#include <math.h>

#define T 2048
#define HD 1024
#define ID 2048
#define NE 8
#define CSTRIDE 32  // counters padded to 128B lines

typedef short bf16x8 __attribute__((ext_vector_type(8)));
typedef float f32x4 __attribute__((ext_vector_type(4)));
typedef unsigned short u16x4 __attribute__((ext_vector_type(4)));

__device__ __forceinline__ unsigned short f2bf(float f) {
  union { float f; unsigned u; } v; v.f = f;
  unsigned r = v.u + 0x7FFFu + ((v.u >> 16) & 1u);
  return (unsigned short)(r >> 16);
}

// cast 4096 fp32 -> bf16 per block; lane-contiguous float4 loads
__device__ __forceinline__ void cast_chunk16(const float* __restrict__ s,
                                             unsigned short* __restrict__ d,
                                             size_t base) {
  size_t o = base + (size_t)threadIdx.x * 4;
#pragma unroll
  for (int k = 0; k < 4; k++) {
    float4 f = *(const float4*)(s + o + k * 1024);
    u16x4 h;
    h[0] = f2bf(f.x); h[1] = f2bf(f.y); h[2] = f2bf(f.z); h[3] = f2bf(f.w);
    *(u16x4*)(d + o + k * 1024) = h;
  }
}

// async global->LDS, 16B per lane; LDS dest = wave-uniform base + lane*16
__device__ __forceinline__ void glds16(const unsigned short* g, unsigned short* l) {
  __builtin_amdgcn_global_load_lds(
      (const __attribute__((address_space(1))) unsigned int*)(g),
      (__attribute__((address_space(3))) unsigned int*)(l), 16, 0, 0);
}

// ---------- prep: router (blocks 0..255, 8 tokens each) +
//                  cast_x (256..767) + cast w1,v (768..8959) ----------
__global__ __launch_bounds__(256) void prep_kernel(
    const float* __restrict__ x, const float* __restrict__ rw,
    const float* __restrict__ w1, const float* __restrict__ v,
    unsigned short* __restrict__ xb, unsigned short* __restrict__ w1b,
    unsigned short* __restrict__ vb, float* __restrict__ logits_out,
    int* __restrict__ pair_rowid, float* __restrict__ pair_gate,
    int* __restrict__ counts) {
  int bx = blockIdx.x;
  if (bx >= 768) {
    int cid = bx - 768;                  // [0, 8192)
    const float* s = (cid < 4096) ? w1 : v;
    unsigned short* d = (cid < 4096) ? w1b : vb;
    cast_chunk16(s, d, (size_t)(cid & 4095) * 4096);
    return;
  }
  if (bx >= 256) {
    cast_chunk16(x, xb, (size_t)(bx - 256) * 4096);
    return;
  }
  __shared__ int s_e[16];
  __shared__ int s_rid[16];
  __shared__ float s_gt[16];
  int tid = threadIdx.x;
  int wid = tid >> 6, lane = tid & 63;
  for (int tk = 0; tk < 2; ++tk) {
    int t = bx * 8 + wid * 2 + tk;
    float acc[NE];
#pragma unroll
    for (int e = 0; e < NE; e++) acc[e] = 0.f;
    const float* xrow = x + (size_t)t * HD;
#pragma unroll 2
    for (int j = 0; j < HD; j += 64) {
      float xv = xrow[j + lane];
#pragma unroll
      for (int e = 0; e < NE; e++) acc[e] += xv * rw[e * HD + j + lane];
    }
#pragma unroll
    for (int e = 0; e < NE; e++)
      for (int off = 32; off > 0; off >>= 1) acc[e] += __shfl_xor(acc[e], off, 64);
    if (lane == 0) {
#pragma unroll
      for (int e = 0; e < NE; e++) logits_out[t * NE + e] = acc[e];
      int e0 = 0;
#pragma unroll
      for (int e = 1; e < NE; e++) if (acc[e] > acc[e0]) e0 = e;
      int e1 = (e0 == 0) ? 1 : 0;
#pragma unroll
      for (int e = 0; e < NE; e++)
        if (e != e0 && e != e1 && acc[e] > acc[e1]) e1 = e;
      float b = __expf(acc[e1] - acc[e0]);
      float g0 = 1.f / (1.f + b);
      float g1 = 1.f - g0;
      int slot = (wid * 2 + tk) * 2;
      s_e[slot] = e0; s_rid[slot] = t * 2;     s_gt[slot] = g0;
      s_e[slot + 1] = e1; s_rid[slot + 1] = t * 2 + 1; s_gt[slot + 1] = g1;
    }
  }
  __syncthreads();
  if (tid < NE) {
    int cnt = 0;
#pragma unroll
    for (int k = 0; k < 16; k++) if (s_e[k] == tid) cnt++;
    if (cnt) {
      int base = atomicAdd(&counts[tid * CSTRIDE], cnt);
      int p = 0;
      for (int k = 0; k < 16; k++)
        if (s_e[k] == tid) {
          pair_rowid[tid * T + base + p] = s_rid[k];
          pair_gate[tid * T + base + p] = s_gt[k];
          p++;
        }
    }
  }
}

// ---------- GEMM1 + fused w2 cast ----------
// blockIdx.x < 32: 128(M)x64(N) tile GEMM1, BK=64, glds16 single-buffer
// blockIdx.x >= 32: cast a 4096-elem chunk of w2 -> w2b (ready before gemm2)
__global__ __launch_bounds__(256) void gemm1_kernel(
    const unsigned short* __restrict__ xb, const unsigned short* __restrict__ w1b,
    const unsigned short* __restrict__ vb, unsigned short* __restrict__ hb,
    const float* __restrict__ w2, unsigned short* __restrict__ w2b,
    const int* __restrict__ pair_rowid, const int* __restrict__ counts) {
  if (blockIdx.x >= 32) {
    int cid = (blockIdx.x - 32) + 32 * (blockIdx.y + 16 * blockIdx.z); // [0,4096)
    cast_chunk16(w2, w2b, (size_t)cid * 4096);
    return;
  }
  int e = blockIdx.z;
  int cnt = counts[e * CSTRIDE];
  int row0 = blockIdx.y * 128;
  if (row0 >= cnt) return;
  __shared__ unsigned short As[128 * 64];
  __shared__ unsigned short B1s[64 * 64];
  __shared__ unsigned short B2s[64 * 64];
  __shared__ int rids[128];
  int tid = threadIdx.x;
  if (tid < 128) {
    int idx = row0 + tid; if (idx > cnt - 1) idx = cnt - 1;
    rids[tid] = pair_rowid[e * T + idx];
  }
  __syncthreads();
  int lane = tid & 63, wid = tid >> 6;
  int wr = wid >> 1, wc = wid & 1;
  int col0 = blockIdx.x * 64;
  int gr = lane >> 3, gc = lane & 7;
  const unsigned short *aA[4], *aB1[2], *aB2[2];
#pragma unroll
  for (int c = 0; c < 4; c++) {
    int row = (c * 4 + wid) * 8 + gr;
    int tok = rids[row] >> 1;
    aA[c] = xb + (size_t)tok * HD + ((gc ^ (row & 7)) * 8);
  }
#pragma unroll
  for (int c = 0; c < 2; c++) {
    int row = (c * 4 + wid) * 8 + gr;
    int kswz = ((gc ^ (row & 7)) * 8);
    aB1[c] = w1b + ((size_t)(e * ID + col0 + row)) * HD + kswz;
    aB2[c] = vb  + ((size_t)(e * ID + col0 + row)) * HD + kswz;
  }
  f32x4 acc1[4][2] = {};
  f32x4 acc3[4][2] = {};
  int mrow = lane & 15, kq = lane >> 4;
  int swzm = mrow & 7;
  for (int kt = 0; kt < HD; kt += 64) {
#pragma unroll
    for (int c = 0; c < 4; c++)
      glds16(aA[c] + kt, &As[(c * 4 + wid) * 512]);
#pragma unroll
    for (int c = 0; c < 2; c++) {
      glds16(aB1[c] + kt, &B1s[(c * 4 + wid) * 512]);
      glds16(aB2[c] + kt, &B2s[(c * 4 + wid) * 512]);
    }
    __syncthreads();
#pragma unroll
    for (int kk = 0; kk < 2; kk++) {
      int g = kk * 4 + kq;
      int ko = ((g ^ swzm) * 8);
      bf16x8 a[4], b1[2], b2[2];
#pragma unroll
      for (int mi = 0; mi < 4; mi++)
        a[mi] = *(const bf16x8*)&As[(wr * 64 + mi * 16 + mrow) * 64 + ko];
#pragma unroll
      for (int ni = 0; ni < 2; ni++) {
        b1[ni] = *(const bf16x8*)&B1s[(wc * 32 + ni * 16 + mrow) * 64 + ko];
        b2[ni] = *(const bf16x8*)&B2s[(wc * 32 + ni * 16 + mrow) * 64 + ko];
      }
#pragma unroll
      for (int mi = 0; mi < 4; mi++)
#pragma unroll
        for (int ni = 0; ni < 2; ni++) {
          acc1[mi][ni] = __builtin_amdgcn_mfma_f32_16x16x32_bf16(a[mi], b1[ni], acc1[mi][ni], 0, 0, 0);
          acc3[mi][ni] = __builtin_amdgcn_mfma_f32_16x16x32_bf16(a[mi], b2[ni], acc3[mi][ni], 0, 0, 0);
        }
    }
    __syncthreads();
  }
  int dcol = lane & 15, drow4 = (lane >> 4) * 4;
#pragma unroll
  for (int mi = 0; mi < 4; mi++)
#pragma unroll
    for (int ni = 0; ni < 2; ni++)
#pragma unroll
      for (int r = 0; r < 4; r++) {
        int lr = wr * 64 + mi * 16 + drow4 + r;
        if (row0 + lr < cnt) {
          float g1v = acc1[mi][ni][r];
          float g3v = acc3[mi][ni][r];
          float hval = 0.5f * g1v * (1.f + erff(g1v * 0.70710678118654752f)) * g3v;
          int rowid = rids[lr];
          hb[(size_t)rowid * ID + col0 + wc * 32 + ni * 16 + dcol] = f2bf(hval);
        }
      }
}

// ---------- GEMM2: 128(M)x64(N) tile, BK=64, glds16 single-buffer ----------
__global__ __launch_bounds__(256) void gemm2_kernel(
    const unsigned short* __restrict__ hb, const unsigned short* __restrict__ w2b,
    float* __restrict__ yb, const int* __restrict__ pair_rowid,
    const float* __restrict__ pair_gate, const int* __restrict__ counts) {
  int e = blockIdx.z;
  int cnt = counts[e * CSTRIDE];
  int row0 = blockIdx.y * 128;
  if (row0 >= cnt) return;
  __shared__ unsigned short As[128 * 64];   // 16 KB
  __shared__ unsigned short Bs[64 * 64];    // 8 KB
  __shared__ int rids[128];
  __shared__ float gts[128];
  int tid = threadIdx.x;
  if (tid < 128) {
    int idx = row0 + tid; if (idx > cnt - 1) idx = cnt - 1;
    rids[tid] = pair_rowid[e * T + idx];
    gts[tid] = pair_gate[e * T + idx];
  }
  __syncthreads();
  int lane = tid & 63, wid = tid >> 6;
  int wr = wid >> 1, wc = wid & 1;
  int col0 = blockIdx.x * 64;
  int gr = lane >> 3, gc = lane & 7;
  const unsigned short *aA[4], *aB[2];
#pragma unroll
  for (int c = 0; c < 4; c++) {
    int row = (c * 4 + wid) * 8 + gr;
    aA[c] = hb + (size_t)rids[row] * ID + ((gc ^ (row & 7)) * 8);
  }
#pragma unroll
  for (int c = 0; c < 2; c++) {
    int row = (c * 4 + wid) * 8 + gr;
    int kswz = ((gc ^ (row & 7)) * 8);
    aB[c] = w2b + ((size_t)(e * HD + col0 + row)) * ID + kswz;
  }
  f32x4 acc[4][2] = {};
  int mrow = lane & 15, kq = lane >> 4;
  int swzm = mrow & 7;
  for (int kt = 0; kt < ID; kt += 64) {
#pragma unroll
    for (int c = 0; c < 4; c++)
      glds16(aA[c] + kt, &As[(c * 4 + wid) * 512]);
#pragma unroll
    for (int c = 0; c < 2; c++)
      glds16(aB[c] + kt, &Bs[(c * 4 + wid) * 512]);
    __syncthreads();
#pragma unroll
    for (int kk = 0; kk < 2; kk++) {
      int g = kk * 4 + kq;
      int ko = ((g ^ swzm) * 8);
      bf16x8 a[4], b[2];
#pragma unroll
      for (int mi = 0; mi < 4; mi++)
        a[mi] = *(const bf16x8*)&As[(wr * 64 + mi * 16 + mrow) * 64 + ko];
#pragma unroll
      for (int ni = 0; ni < 2; ni++)
        b[ni] = *(const bf16x8*)&Bs[(wc * 32 + ni * 16 + mrow) * 64 + ko];
#pragma unroll
      for (int mi = 0; mi < 4; mi++)
#pragma unroll
        for (int ni = 0; ni < 2; ni++)
          acc[mi][ni] = __builtin_amdgcn_mfma_f32_16x16x32_bf16(a[mi], b[ni], acc[mi][ni], 0, 0, 0);
    }
    __syncthreads();
  }
  int dcol = lane & 15, drow4 = (lane >> 4) * 4;
#pragma unroll
  for (int mi = 0; mi < 4; mi++)
#pragma unroll
    for (int ni = 0; ni < 2; ni++)
#pragma unroll
      for (int r = 0; r < 4; r++) {
        int lr = wr * 64 + mi * 16 + drow4 + r;
        if (row0 + lr < cnt) {
          float val = gts[lr] * acc[mi][ni][r];
          yb[(size_t)rids[lr] * HD + col0 + wc * 32 + ni * 16 + dcol] = val;
        }
      }
}

// ---------- combine: out[t] = yb[2t] + yb[2t+1] ----------
__global__ __launch_bounds__(256) void combine_kernel(
    const float* __restrict__ yb, float* __restrict__ out) {
  size_t t = blockIdx.x;
  int c = threadIdx.x * 4;
  float4 a = *(const float4*)(yb + (t * 2) * HD + c);
  float4 b = *(const float4*)(yb + (t * 2 + 1) * HD + c);
  float4 o;
  o.x = a.x + b.x; o.y = a.y + b.y; o.z = a.z + b.z; o.w = a.w + b.w;
  *(float4*)(out + t * HD + c) = o;
}

extern "C" void kernel_launch(void* const* d_in, const int* in_sizes, int n_in,
                              void* d_out, int out_size, void* d_ws, size_t ws_size,
                              hipStream_t stream) {
  const float* x  = (const float*)d_in[0];
  const float* rw = (const float*)d_in[1];
  const float* w1 = (const float*)d_in[2];
  const float* v  = (const float*)d_in[3];
  const float* w2 = (const float*)d_in[4];
  float* out = (float*)d_out;
  float* logits_out = out + (size_t)T * HD;

  char* ws = (char*)d_ws;
  unsigned short* xb  = (unsigned short*)(ws);                      // 4 MB
  unsigned short* hb  = (unsigned short*)(ws + (4u << 20));         // 16 MB
  unsigned short* w1b = (unsigned short*)(ws + (20u << 20));        // 32 MB
  unsigned short* vb  = (unsigned short*)(ws + (52u << 20));        // 32 MB
  unsigned short* w2b = (unsigned short*)(ws + (84u << 20));        // 32 MB
  float* yb           = (float*)(ws + (20u << 20));                 // 16 MB, overlays w1b (dead after gemm1)
  int*   pair_rowid   = (int*)  (ws + (116u << 20));                // 64 KB
  float* pair_gate    = (float*)(ws + (116u << 20) + 65536);        // 64 KB
  int*   counts       = (int*)  (ws + (116u << 20) + 131072);       // 1 KB

  hipMemsetAsync(counts, 0, NE * CSTRIDE * sizeof(int), stream);

  // prep: 256 router + 512 x-cast + 8192 w1/v-cast
  prep_kernel<<<8960, 256, 0, stream>>>(x, rw, w1, v, xb, w1b, vb,
                                        logits_out, pair_rowid, pair_gate,
                                        counts);
  // gemm1 (x<32) + w2 cast (x>=32, ready before gemm2 by stream order)
  gemm1_kernel<<<dim3(ID / 64 + 32, T / 128, NE), 256, 0, stream>>>(
      xb, w1b, vb, hb, w2, w2b, pair_rowid, counts);
  gemm2_kernel<<<dim3(HD / 64, T / 128, NE), 256, 0, stream>>>(
      hb, w2b, yb, pair_rowid, pair_gate, counts);
  combine_kernel<<<T, 256, 0, stream>>>(yb, out);
}